// Round 7
// baseline (151.430 us; speedup 1.0000x reference)
//
#include <hip/hip_runtime.h>

// NGF loss: g = normalized gradient (central diff interior, one-sided at edges),
// loss = 1 - mean( (g0 . g1)^2 ).  B=64, C=1, H=512, W=512, fp32.
//
// R7: hand-pinned load pipeline. R1-R6 all compiled to VGPR<=68: the pre-RA
// scheduler serializes loads regardless of launch bounds / fences / window
// structure => ~3 TB/s effective, 43-48us, no pipe >33% busy. Here every
// staging load is an opaque inline-asm global_load_dwordx4 (cannot be sunk,
// reused, or analyzed), issued 40-deep per thread, consumed under manual
// descending s_waitcnt vmcnt(28..0) with register-tying so the compiler
// cannot read a dest register before its wait. Wave owns 8 rows x 512 cols;
// lane l owns cols [8l,8l+8); W-halos via intra-wave shfl; H-edge chunks
// (ck 0 and 63, 3% of waves) use a plain C++ fallback (wave-uniform branch).

#define HH 512
#define WW 512
#define NGF_EPS 1e-10f
#define RPT 8   // rows per wave

typedef float vf4 __attribute__((ext_vector_type(4)));

__device__ __forceinline__ float rcp_fast(float x) { return __builtin_amdgcn_rcpf(x); }

// One image row's contribution for this lane (8 cols), given 3-row window.
// u = row h-1 (clamped), c = row h, n = row h+1 (clamped); a/b = col halves.
__device__ __forceinline__ float row_contrib(int lane,
        vf4 u0a, vf4 u0b, vf4 c0a, vf4 c0b, vf4 n0a, vf4 n0b,
        vf4 u1a, vf4 u1b, vf4 c1a, vf4 c1b, vf4 n1a, vf4 n1b) {
    float L0 = __shfl_up(c0b.w, 1, 64);   if (lane == 0)  L0 = c0a.x;
    float R0 = __shfl_down(c0a.x, 1, 64); if (lane == 63) R0 = c0b.w;
    float L1 = __shfl_up(c1b.w, 1, 64);   if (lane == 0)  L1 = c1a.x;
    float R1 = __shfl_down(c1a.x, 1, 64); if (lane == 63) R1 = c1b.w;

    const float a0[10] = {L0, c0a.x, c0a.y, c0a.z, c0a.w, c0b.x, c0b.y, c0b.z, c0b.w, R0};
    const float a1[10] = {L1, c1a.x, c1a.y, c1a.z, c1a.w, c1b.x, c1b.y, c1b.z, c1b.w, R1};
    const float gx0[8] = {n0a.x - u0a.x, n0a.y - u0a.y, n0a.z - u0a.z, n0a.w - u0a.w,
                          n0b.x - u0b.x, n0b.y - u0b.y, n0b.z - u0b.z, n0b.w - u0b.w};
    const float gx1[8] = {n1a.x - u1a.x, n1a.y - u1a.y, n1a.z - u1a.z, n1a.w - u1a.w,
                          n1b.x - u1b.x, n1b.y - u1b.y, n1b.z - u1b.z, n1b.w - u1b.w};
    float s = 0.f;
#pragma unroll
    for (int j = 0; j < 8; ++j) {
        const float gy0 = a0[j + 2] - a0[j];
        const float gy1 = a1[j + 2] - a1[j];
        const float q0  = gx0[j] * gx0[j] + gy0 * gy0 + NGF_EPS;
        const float q1  = gx1[j] * gx1[j] + gy1 * gy1 + NGF_EPS;
        const float cr  = gx0[j] * gx1[j] + gy0 * gy1;
        s += cr * cr * rcp_fast(q0 * q1);   // dot^2 = cross^2/(n0*n1)
    }
    return s;
}

// Opaque load: compiler cannot sink it, reuse its dest, or analyze the memory.
#define LD(dst, base, OFF) \
    asm volatile("global_load_dwordx4 %0, %1, off offset:" #OFF \
                 : "=v"(dst) : "v"(base))
// All 4 f4 loads of staged row j (both images).
#define LDROW(j, b, OA, OB)      \
    LD(A0a[j], B0[b], OA); LD(A0b[j], B0[b], OB); \
    LD(A1a[j], B1[b], OA); LD(A1b[j], B1[b], OB)
// Wait until staged row j's loads are complete (N = loads still allowed
// outstanding), and tie row j's registers so consumers sit after the wait.
#define TIE(j, N) \
    asm volatile("s_waitcnt vmcnt(" #N ")" \
                 : "+v"(A0a[j]), "+v"(A0b[j]), "+v"(A1a[j]), "+v"(A1b[j]))
// Contribution of compute row i (staged rows i, i+1, i+2 as u/c/n).
#define ROWC(i) row_contrib(lane, \
        A0a[i], A0b[i], A0a[(i)+1], A0b[(i)+1], A0a[(i)+2], A0b[(i)+2], \
        A1a[i], A1b[i], A1a[(i)+1], A1b[(i)+1], A1a[(i)+2], A1b[(i)+2])

// waves = 64 imgs * 64 chunks = 4096 -> 1024 blocks x 256 threads
__global__ __launch_bounds__(256, 1) void ngf_partial(const float* I0,
                                                      const float* I1,
                                                      float* partials) {
    const int tid  = threadIdx.x;
    const int wv   = tid >> 6;
    const int lane = tid & 63;
    const int gw   = blockIdx.x * 4 + wv;   // 0..4095
    const int img  = gw >> 6;
    const int ck   = gw & 63;               // row chunk; rows [ck*8, ck*8+8)
    const int h0   = ck * RPT;

    const float* p0 = I0 + (size_t)img * (HH * WW) + lane * 8;
    const float* p1 = I1 + (size_t)img * (HH * WW) + lane * 8;

    float s = 0.f;

    if (ck != 0 && ck != 63) {
        // Interior: staged rows j=0..9 <-> global rows h0-1 .. h0+8 (no clamp).
        // Bases at staged rows 0,2,4,6,8; odd rows via offset:2048/2064.
        uint64_t B0[5], B1[5];
#pragma unroll
        for (int b = 0; b < 5; ++b) {
            B0[b] = (uint64_t)(p0 + (h0 - 1 + 2 * b) * WW);
            B1[b] = (uint64_t)(p1 + (h0 - 1 + 2 * b) * WW);
        }
        vf4 A0a[10], A0b[10], A1a[10], A1b[10];
        // 40 loads, issued back-to-back (asm volatile preserves mutual order).
        LDROW(0, 0, 0, 16);  LDROW(1, 0, 2048, 2064);
        LDROW(2, 1, 0, 16);  LDROW(3, 1, 2048, 2064);
        LDROW(4, 2, 0, 16);  LDROW(5, 2, 2048, 2064);
        LDROW(6, 3, 0, 16);  LDROW(7, 3, 2048, 2064);
        LDROW(8, 4, 0, 16);  LDROW(9, 4, 2048, 2064);

        // Descending waits: row i needs staged rows <= i+2 complete.
        TIE(0, 28); TIE(1, 28); TIE(2, 28);
        s += ROWC(0);
        TIE(3, 24); s += ROWC(1);
        TIE(4, 20); s += ROWC(2);
        TIE(5, 16); s += ROWC(3);
        TIE(6, 12); s += ROWC(4);
        TIE(7, 8);  s += ROWC(5);
        TIE(8, 4);  s += ROWC(6);
        TIE(9, 0);  s += ROWC(7);
    } else {
        // H-edge chunks (first/last 8 rows of an image): simple fallback.
#pragma unroll
        for (int i = 0; i < RPT; ++i) {
            const int h  = h0 + i;
            const int hu = (h > 0) ? h - 1 : 0;
            const int hd = (h < HH - 1) ? h + 1 : HH - 1;
            const vf4* u0 = (const vf4*)(p0 + hu * WW);
            const vf4* c0 = (const vf4*)(p0 + h * WW);
            const vf4* n0 = (const vf4*)(p0 + hd * WW);
            const vf4* u1 = (const vf4*)(p1 + hu * WW);
            const vf4* c1 = (const vf4*)(p1 + h * WW);
            const vf4* n1 = (const vf4*)(p1 + hd * WW);
            s += row_contrib(lane, u0[0], u0[1], c0[0], c0[1], n0[0], n0[1],
                                   u1[0], u1[1], c1[0], c1[1], n1[0], n1[1]);
        }
    }

    // wave64 reduce; lane 0 writes this wave's partial.
#pragma unroll
    for (int off = 32; off > 0; off >>= 1) s += __shfl_down(s, off, 64);
    if (lane == 0) partials[gw] = s;
}

// 4096 partials: 1024 threads x float4, one block.
__global__ __launch_bounds__(1024) void ngf_finalize(const float4* __restrict__ partials,
                                                     float inv_n,
                                                     float* __restrict__ out) {
    const float4 v = partials[threadIdx.x];
    float s = v.x + v.y + v.z + v.w;
#pragma unroll
    for (int off = 32; off > 0; off >>= 1) s += __shfl_down(s, off, 64);

    __shared__ float lds[16];
    const int wave = threadIdx.x >> 6;
    const int lane = threadIdx.x & 63;
    if (lane == 0) lds[wave] = s;
    __syncthreads();
    if (threadIdx.x == 0) {
        float tot = 0.f;
#pragma unroll
        for (int i = 0; i < 16; ++i) tot += lds[i];
        out[0] = 1.0f - tot * inv_n;
    }
}

extern "C" void kernel_launch(void* const* d_in, const int* in_sizes, int n_in,
                              void* d_out, int out_size, void* d_ws, size_t ws_size,
                              hipStream_t stream) {
    const float* I0 = (const float*)d_in[0];
    const float* I1 = (const float*)d_in[1];
    float* partials = (float*)d_ws;          // 4096 floats = 16 KB

    const int N = in_sizes[0];               // 16,777,216
    ngf_partial<<<1024, 256, 0, stream>>>(I0, I1, partials);
    ngf_finalize<<<1, 1024, 0, stream>>>((const float4*)partials,
                                         1.0f / (float)N, (float*)d_out);
}

// Round 9
// 142.300 us; speedup vs baseline: 1.0642x; 1.0642x over previous
//
#include <hip/hip_runtime.h>

// NGF loss: g = normalized gradient (central diff interior, one-sided at edges),
// loss = 1 - mean( (g0 . g1)^2 ).  B=64, C=1, H=512, W=512, fp32.
//
// R9 = R8 with the compile fix: __builtin_nontemporal_load requires a clang
// ext_vector_type, not HIP's float4 struct. Same theory: seven structures all
// pin at 134MB / 43-48us ~= 3.1 TB/s regardless of per-wave MLP, occupancy,
// or staging path => per-CU outstanding-request capacity (~34 lines at 900cy,
// matching the m13 copy benchmark's ~3.15 TB/s read half). NT loads are the
// last untested lever: if L1 allocate slots serialize requests, nt bypasses
// them; if the TA queue is shared, we land at ~43.5us = read-stream roofline.

#define HH 512
#define WW 512
#define NGF_EPS 1e-10f
#define RPT 16   // rows walked per wave

typedef float vf4 __attribute__((ext_vector_type(4)));

__device__ __forceinline__ float rcp_fast(float x) { return __builtin_amdgcn_rcpf(x); }
__device__ __forceinline__ vf4 ldnt(const float* p) {
    return __builtin_nontemporal_load((const vf4*)p);
}

// waves = 64 imgs * (512/RPT = 32 chunks) = 2048 -> 512 blocks x 256 threads
__global__ __launch_bounds__(256) void ngf_partial(const float* __restrict__ I0,
                                                   const float* __restrict__ I1,
                                                   float* __restrict__ partials) {
    const int tid  = threadIdx.x;
    const int wv   = tid >> 6;
    const int lane = tid & 63;
    const int gw   = blockIdx.x * 4 + wv;   // global wave id, 0..2047
    const int img  = gw >> 5;               // 0..63
    const int ck   = gw & 31;               // row-chunk 0..31
    const int h0   = ck * RPT;

    const float* p0 = I0 + (size_t)img * (HH * WW) + lane * 8;
    const float* p1 = I1 + (size_t)img * (HH * WW) + lane * 8;

    // 3-row window (u = h-1 clamped, c = h, n = h+1) + prefetch m = h+2.
    vf4 u0a, u0b, u1a, u1b, c0a, c0b, c1a, c1b, n0a, n0b, n1a, n1b;
    {
        const int ru = (h0 > 0) ? (h0 - 1) * WW : 0;
        const int rc = h0 * WW;
        const int rn = (h0 + 1) * WW;       // h0 <= 496 -> always valid
        u0a = ldnt(p0 + ru);     u0b = ldnt(p0 + ru + 4);
        u1a = ldnt(p1 + ru);     u1b = ldnt(p1 + ru + 4);
        c0a = ldnt(p0 + rc);     c0b = ldnt(p0 + rc + 4);
        c1a = ldnt(p1 + rc);     c1b = ldnt(p1 + rc + 4);
        n0a = ldnt(p0 + rn);     n0b = ldnt(p0 + rn + 4);
        n1a = ldnt(p1 + rn);     n1b = ldnt(p1 + rn + 4);
    }

    float s = 0.f;
#pragma unroll
    for (int i = 0; i < RPT; ++i) {
        const int h  = h0 + i;
        const int hm = (h + 2 < HH) ? h + 2 : HH - 1;     // prefetch row, clamped
        const int rm = hm * WW;
        const vf4 m0a = ldnt(p0 + rm);
        const vf4 m0b = ldnt(p0 + rm + 4);
        const vf4 m1a = ldnt(p1 + rm);
        const vf4 m1b = ldnt(p1 + rm + 4);

        // W-halos from neighbors' center-row registers; image edges clamp.
        float L0 = __shfl_up(c0b.w, 1, 64);   if (lane == 0)  L0 = c0a.x;
        float R0 = __shfl_down(c0a.x, 1, 64); if (lane == 63) R0 = c0b.w;
        float L1 = __shfl_up(c1b.w, 1, 64);   if (lane == 0)  L1 = c1a.x;
        float R1 = __shfl_down(c1a.x, 1, 64); if (lane == 63) R1 = c1b.w;

        const float a0[10] = {L0, c0a.x, c0a.y, c0a.z, c0a.w,
                                  c0b.x, c0b.y, c0b.z, c0b.w, R0};
        const float a1[10] = {L1, c1a.x, c1a.y, c1a.z, c1a.w,
                                  c1b.x, c1b.y, c1b.z, c1b.w, R1};
        const float gx0[8] = {n0a.x - u0a.x, n0a.y - u0a.y, n0a.z - u0a.z, n0a.w - u0a.w,
                              n0b.x - u0b.x, n0b.y - u0b.y, n0b.z - u0b.z, n0b.w - u0b.w};
        const float gx1[8] = {n1a.x - u1a.x, n1a.y - u1a.y, n1a.z - u1a.z, n1a.w - u1a.w,
                              n1b.x - u1b.x, n1b.y - u1b.y, n1b.z - u1b.z, n1b.w - u1b.w};
#pragma unroll
        for (int j = 0; j < 8; ++j) {
            const float gy0 = a0[j + 2] - a0[j];
            const float gy1 = a1[j + 2] - a1[j];
            const float q0  = gx0[j] * gx0[j] + gy0 * gy0 + NGF_EPS;
            const float q1  = gx1[j] * gx1[j] + gy1 * gy1 + NGF_EPS;
            const float cr  = gx0[j] * gx1[j] + gy0 * gy1;
            s += cr * cr * rcp_fast(q0 * q1);   // dot^2 = cross^2/(n0*n1)
        }
        // rotate window (pure register renaming under full unroll)
        u0a = c0a; u0b = c0b; u1a = c1a; u1b = c1b;
        c0a = n0a; c0b = n0b; c1a = n1a; c1b = n1b;
        n0a = m0a; n0b = m0b; n1a = m1a; n1b = m1b;
    }

    // wave64 reduce; lane 0 writes this wave's partial directly (no LDS).
#pragma unroll
    for (int off = 32; off > 0; off >>= 1) s += __shfl_down(s, off, 64);
    if (lane == 0) partials[gw] = s;
}

// 2048 partials: 512 threads x vf4, one block.
__global__ __launch_bounds__(512) void ngf_finalize(const float* __restrict__ partials,
                                                    float inv_n,
                                                    float* __restrict__ out) {
    const vf4 v = *(const vf4*)(partials + threadIdx.x * 4);
    float s = v.x + v.y + v.z + v.w;
#pragma unroll
    for (int off = 32; off > 0; off >>= 1) s += __shfl_down(s, off, 64);

    __shared__ float lds[8];
    const int wave = threadIdx.x >> 6;
    const int lane = threadIdx.x & 63;
    if (lane == 0) lds[wave] = s;
    __syncthreads();
    if (threadIdx.x == 0) {
        float tot = 0.f;
#pragma unroll
        for (int i = 0; i < 8; ++i) tot += lds[i];
        out[0] = 1.0f - tot * inv_n;
    }
}

extern "C" void kernel_launch(void* const* d_in, const int* in_sizes, int n_in,
                              void* d_out, int out_size, void* d_ws, size_t ws_size,
                              hipStream_t stream) {
    const float* I0 = (const float*)d_in[0];
    const float* I1 = (const float*)d_in[1];
    float* partials = (float*)d_ws;          // 2048 floats = 8 KB

    const int N = in_sizes[0];               // 16,777,216
    ngf_partial<<<512, 256, 0, stream>>>(I0, I1, partials);
    ngf_finalize<<<1, 512, 0, stream>>>(partials, 1.0f / (float)N, (float*)d_out);
}